// Round 7
// baseline (236.302 us; speedup 1.0000x reference)
//
#include <hip/hip_runtime.h>
#include <hip/hip_bf16.h>
#include <float.h>

// N=1024, M=1024, D=512, fp32.
// tanh(q+k) = 1 - 2/(1+exp2(CS*(q+k))), CS=2*log2(e), exp2 factorized:
// eqT[d][n]=min(exp2(CS*qp),2^13)^T, ek[m][d]=min(exp2(CS*kp),2^13).
// Score s[n,m] = -2*sum_d Ww[d]/(1+eq*ek) (row-const dropped; softmax
// shift-invariant; exp never overflows -> no max pass). Quad-rational merges
// 4 d-terms into ONE rcp (rcp is 1/8-rate). PT[m][n] = mask?exp(s):0.
// ctx folds rowsum + normalize. 3 kernels.
// R7: score scalar-load stall fixed (Ww via LDS, ek via VMEM); proj/ctx
// occupancy fixed (in-block split-K 512thr / 512-block grid + prefetch).
// ws (floats): eqT[512K] ek[512K] vp[512K] PT[1M] = 10.5 MB.

#define NROWS 1024
#define DDIM  512
#define MDIM  1024

__device__ __forceinline__ void load_lds16(const float* g, float* l) {
    __builtin_amdgcn_global_load_lds(
        (const __attribute__((address_space(1))) void*)g,
        (__attribute__((address_space(3))) void*)l, 16, 0, 0);
}

// ---------------- Fused projection GEMMs (A^T-B form, in-block split-K) ------
// out[R][C] = sum_k A[r][k]*B[c][k] (+bias, optional clamp(exp2*CS)).
// z=0: eqT[d][n]: A=Wq, B=q,  bias row,  exp2.  R=512,  C=1024
// z=1: ek[m][d]:  A=k,  B=Wk, bias col,  exp2.  R=1024, C=512
// z=2: vp[m][d]:  A=v,  B=Wv, bias col.         R=1024, C=512
// 512 threads = 2 teams of 256; team h accumulates k in [h*256,(h+1)*256);
// team1's acc added to team0's through LDS; team0 does the epilogue.
// LDS k-major, 16B-block XOR swizzle (conflict-free stores + b128 reads).
// Register prefetch of next K-chunk hides global latency.
__global__ __launch_bounds__(512) void proj_gemm(
    const float* __restrict__ q, const float* __restrict__ kk_,
    const float* __restrict__ v,
    const float* __restrict__ Wq, const float* __restrict__ bq,
    const float* __restrict__ Wk, const float* __restrict__ bk,
    const float* __restrict__ Wv, const float* __restrict__ bv,
    float* __restrict__ eqT, float* __restrict__ ek, float* __restrict__ vp,
    float CS)
{
    __shared__ __align__(16) float lds[16384];   // 64 KB: As0|Bs0|As1|Bs1

    const float* A; const float* B; const float* bias; float* out;
    int C, expo, biasRow;
    if (blockIdx.z == 0)      { A = Wq;  B = q;  bias = bq; out = eqT; C = 1024; expo = 1; biasRow = 1; }
    else if (blockIdx.z == 1) { A = kk_; B = Wk; bias = bk; out = ek;  C = 512;  expo = 1; biasRow = 0; }
    else                      { A = v;   B = Wv; bias = bv; out = vp;  C = 512;  expo = 0; biasRow = 0; }

    const int bi = (blockIdx.z == 0) ? blockIdx.y : blockIdx.x;   // R tile
    const int bj = (blockIdx.z == 0) ? blockIdx.x : blockIdx.y;   // C tile

    const int t    = threadIdx.x;
    const int team = t >> 8;
    const int tt   = t & 255;
    const int tx   = tt & 15;
    const int ty   = tt >> 4;
    const int i0   = bi * 64;
    const int j0   = bj * 64;

    float* As = lds + team * 8192;
    float* Bs = lds + team * 8192 + 4096;

    float acc[4][4] = {};
    float4 pa[4], pb[4];

    // prefetch chunk 0
    {
        const int k0 = team * 256;
#pragma unroll
        for (int p = 0; p < 4; ++p) {
            int idx = tt + p * 256;
            int r = idx >> 4, c4 = idx & 15;
            pa[p] = *(const float4*)&A[(size_t)(i0 + r) * DDIM + k0 + c4 * 4];
            pb[p] = *(const float4*)&B[(size_t)(j0 + r) * DDIM + k0 + c4 * 4];
        }
    }

    for (int kc = 0; kc < 4; ++kc) {
        __syncthreads();
#pragma unroll
        for (int p = 0; p < 4; ++p) {
            int idx = tt + p * 256;
            int r = idx >> 4, c4 = idx & 15;
            int base = (c4 * 4) * 64 + (((r >> 2) ^ c4) << 2) + (r & 3);
            As[base]       = pa[p].x;  As[base + 64]  = pa[p].y;
            As[base + 128] = pa[p].z;  As[base + 192] = pa[p].w;
            Bs[base]       = pb[p].x;  Bs[base + 64]  = pb[p].y;
            Bs[base + 128] = pb[p].z;  Bs[base + 192] = pb[p].w;
        }
        __syncthreads();
        if (kc < 3) {
            const int k0 = team * 256 + (kc + 1) * 64;
#pragma unroll
            for (int p = 0; p < 4; ++p) {
                int idx = tt + p * 256;
                int r = idx >> 4, c4 = idx & 15;
                pa[p] = *(const float4*)&A[(size_t)(i0 + r) * DDIM + k0 + c4 * 4];
                pb[p] = *(const float4*)&B[(size_t)(j0 + r) * DDIM + k0 + c4 * 4];
            }
        }
#pragma unroll
        for (int kg = 0; kg < 16; ++kg) {
            const int ao = ((ty ^ kg) << 2);
            const int bo = ((tx ^ kg) << 2);
#pragma unroll
            for (int kq = 0; kq < 4; ++kq) {
                int kk = kg * 4 + kq;
                float4 a = *(const float4*)&As[kk * 64 + ao];
                float4 b = *(const float4*)&Bs[kk * 64 + bo];
                float av4[4] = {a.x, a.y, a.z, a.w};
                float bv4[4] = {b.x, b.y, b.z, b.w};
#pragma unroll
                for (int i = 0; i < 4; ++i)
#pragma unroll
                    for (int j = 0; j < 4; ++j)
                        acc[i][j] = fmaf(av4[i], bv4[j], acc[i][j]);
            }
        }
    }

    // cross-team reduce: team1 -> scratch (stride 20, 16B-aligned), team0 adds
    __syncthreads();
    float* scratch = lds;                       // reuses As0/Bs0
    if (team == 1) {
#pragma unroll
        for (int i = 0; i < 4; ++i) {
            float4 o = {acc[i][0], acc[i][1], acc[i][2], acc[i][3]};
            *(float4*)&scratch[tt * 20 + i * 4] = o;
        }
    }
    __syncthreads();
    if (team == 0) {
        const float CLAMP = 8192.0f;   // 2^13: quad-rational den < 2^127
#pragma unroll
        for (int i = 0; i < 4; ++i) {
            float4 s = *(const float4*)&scratch[tt * 20 + i * 4];
            acc[i][0] += s.x; acc[i][1] += s.y; acc[i][2] += s.z; acc[i][3] += s.w;
            int row = i0 + ty * 4 + i;
            float ov[4];
#pragma unroll
            for (int j = 0; j < 4; ++j) {
                float bval = biasRow ? bias[row] : bias[j0 + tx * 4 + j];
                float val = acc[i][j] + bval;
                ov[j] = expo ? fminf(__builtin_amdgcn_exp2f(val * CS), CLAMP) : val;
            }
            float4 o = {ov[0], ov[1], ov[2], ov[3]};
            *(float4*)&out[(size_t)row * C + j0 + tx * 4] = o;
        }
    }
}

// ---------------- Score kernel ----------------------------------------------
// PT[m][n] = mask[n][m] ? exp(-2*sum_d Ww[d]/(1+eqT[d][n]*ek[m][d])) : 0
// 4 waves; wave w owns ONE m (vmem-loaded quads: divergence-opaque address ->
// global_load_dwordx4, vmcnt); Ww staged ONCE in LDS (homogeneous lgkmcnt).
// eqT chunk [32 d][256 n] via global_load_lds width=16. Grid 1024 = 4/CU.
#define DCH 32
__global__ __launch_bounds__(256) void score_kernel(const float* __restrict__ eqT,
                                                    const float* __restrict__ ek,
                                                    const float* __restrict__ Ww,
                                                    const int* __restrict__ mask,
                                                    float* __restrict__ PT)
{
    __shared__ __align__(16) float ks[DCH * 256];   // 32 KB
    __shared__ __align__(16) float wws[512];        // 2 KB, staged once
    const int t    = threadIdx.x;
    const int lane = t & 63;
    const int w    = t >> 6;
    const int n0   = blockIdx.x * 256;
    const int m    = blockIdx.y * 4 + w;            // NOT readfirstlane'd:
    const float* __restrict__ ekrow = ek + (size_t)m * DDIM;  // keeps VMEM path

    wws[t] = Ww[t];
    wws[t + 256] = Ww[t + 256];

    float acc[4] = {};

    for (int d0 = 0; d0 < DDIM; d0 += DCH) {
        __syncthreads();
#pragma unroll
        for (int i = 0; i < 8; ++i) {
            int r = w * 8 + i;                                   // wave-uniform
            load_lds16(eqT + (size_t)(d0 + r) * NROWS + n0 + lane * 4,
                       &ks[r * 256]);
        }
        __syncthreads();   // drains vmcnt -> global_load_lds data visible

#pragma unroll
        for (int dq = 0; dq < DCH; dq += 4) {
            float4 eg = *(const float4*)&ekrow[d0 + dq];         // vmcnt
            float4 wg = *(const float4*)&wws[d0 + dq];           // lgkm (DS only)
            float4 k0 = *(const float4*)&ks[(dq + 0) * 256 + lane * 4];
            float4 k1 = *(const float4*)&ks[(dq + 1) * 256 + lane * 4];
            float4 k2 = *(const float4*)&ks[(dq + 2) * 256 + lane * 4];
            float4 k3 = *(const float4*)&ks[(dq + 3) * 256 + lane * 4];
            float kv0[4] = {k0.x, k0.y, k0.z, k0.w};
            float kv1[4] = {k1.x, k1.y, k1.z, k1.w};
            float kv2[4] = {k2.x, k2.y, k2.z, k2.w};
            float kv3[4] = {k3.x, k3.y, k3.z, k3.w};
#pragma unroll
            for (int j = 0; j < 4; ++j) {
                float A0 = fmaf(kv0[j], eg.x, 1.0f);
                float A1 = fmaf(kv1[j], eg.y, 1.0f);
                float A2 = fmaf(kv2[j], eg.z, 1.0f);
                float A3 = fmaf(kv3[j], eg.w, 1.0f);
                float n01 = fmaf(wg.y, A0, wg.x * A1);
                float d01 = A0 * A1;
                float n23 = fmaf(wg.w, A2, wg.z * A3);
                float d23 = A2 * A3;
                float num = fmaf(n01, d23, n23 * d01);
                float den = d01 * d23;
                acc[j] = fmaf(num, __builtin_amdgcn_rcpf(den), acc[j]);
            }
        }
    }

    const float C2 = -2.8853900817779268f;   // -2*log2(e)
    const int nb = n0 + lane * 4;
    float ov[4];
#pragma unroll
    for (int j = 0; j < 4; ++j) {
        int mk = mask[(size_t)(nb + j) * MDIM + m];
        ov[j] = mk ? __builtin_amdgcn_exp2f(acc[j] * C2) : 0.f;
    }
    float4 o = {ov[0], ov[1], ov[2], ov[3]};
    *(float4*)&PT[(size_t)m * NROWS + nb] = o;
}

// ---------------- Context GEMM + folded rowsum + normalize -------------------
// out[n][d] = (sum_m PT[m][n]*vp[m][d]) / (sum_m PT[m][n])
// 32(n) x 32(d) tile, grid (16 d,32 n) = 512 blocks (2/CU). Register prefetch
// of the next m-chunk; rowsums folded into PT staging.
__global__ __launch_bounds__(256) void ctx_gemm(const float* __restrict__ PT,
                                                const float* __restrict__ vp,
                                                float* __restrict__ out)
{
    __shared__ __align__(16) float pts[64 * 34];   // [m][n]
    __shared__ __align__(16) float vs[64 * 34];    // [m][d]
    __shared__ __align__(16) float psc[1024];
    __shared__ float rinvs[32];
    const int t  = threadIdx.x;
    const int tx = t & 15;      // d-frag (2 d)
    const int ty = t >> 4;      // n-frag (2 n)
    const int n0 = blockIdx.y * 32;
    const int d0 = blockIdx.x * 32;

    float acc[2][2] = {};
    float psum[4] = {};          // rowsums for n = n0+(t&7)*4+j

    float4 rp[2], rv[2];
#pragma unroll
    for (int p = 0; p < 2; ++p) {
        int idx = t + p * 256;
        int r = idx >> 3, c4 = idx & 7;
        rp[p] = *(const float4*)&PT[(size_t)r * NROWS + n0 + c4 * 4];
        rv[p] = *(const float4*)&vp[(size_t)r * DDIM + d0 + c4 * 4];
    }

    for (int m0 = 0; m0 < MDIM; m0 += 64) {
        __syncthreads();
#pragma unroll
        for (int p = 0; p < 2; ++p) {
            int idx = t + p * 256;
            int r = idx >> 3, c4 = idx & 7;
            *(float4*)&pts[r * 34 + c4 * 4] = rp[p];
            psum[0] += rp[p].x; psum[1] += rp[p].y;
            psum[2] += rp[p].z; psum[3] += rp[p].w;
            *(float4*)&vs[r * 34 + c4 * 4] = rv[p];
        }
        __syncthreads();
        if (m0 + 64 < MDIM) {
#pragma unroll
            for (int p = 0; p < 2; ++p) {
                int idx = t + p * 256;
                int r = idx >> 3, c4 = idx & 7;
                rp[p] = *(const float4*)&PT[(size_t)(m0 + 64 + r) * NROWS + n0 + c4 * 4];
                rv[p] = *(const float4*)&vp[(size_t)(m0 + 64 + r) * DDIM + d0 + c4 * 4];
            }
        }
#pragma unroll 16
        for (int mm = 0; mm < 64; ++mm) {
            float2 a = *(const float2*)&pts[mm * 34 + ty * 2];   // broadcast
            float2 b = *(const float2*)&vs[mm * 34 + tx * 2];
            acc[0][0] = fmaf(a.x, b.x, acc[0][0]);
            acc[0][1] = fmaf(a.x, b.y, acc[0][1]);
            acc[1][0] = fmaf(a.y, b.x, acc[1][0]);
            acc[1][1] = fmaf(a.y, b.y, acc[1][1]);
        }
    }

    // rowsum reduce: psc[t*4..] then 32 threads fold 32 partials each
    __syncthreads();
    float4 ps = {psum[0], psum[1], psum[2], psum[3]};
    *(float4*)&psc[t * 4] = ps;
    __syncthreads();
    if (t < 32) {
        int j = t & 3, c4 = t >> 2;
        float tot = 0.f;
#pragma unroll
        for (int g = 0; g < 32; ++g) tot += psc[(c4 + 8 * g) * 4 + j];
        rinvs[t] = __builtin_amdgcn_rcpf(tot);   // rinvs[nl], nl = c4*4+j = t
    }
    __syncthreads();

#pragma unroll
    for (int i = 0; i < 2; ++i) {
        int nl = ty * 2 + i;
        float inv = rinvs[nl];
        float2 o = {acc[i][0] * inv, acc[i][1] * inv};
        *(float2*)&out[(size_t)(n0 + nl) * DDIM + d0 + tx * 2] = o;
    }
}

extern "C" void kernel_launch(void* const* d_in, const int* in_sizes, int n_in,
                              void* d_out, int out_size, void* d_ws, size_t ws_size,
                              hipStream_t stream)
{
    const float* q    = (const float*)d_in[0];
    const float* k    = (const float*)d_in[1];
    const float* v    = (const float*)d_in[2];
    const int*   mask = (const int*)d_in[3];
    const float* Wq   = (const float*)d_in[4];
    const float* bq   = (const float*)d_in[5];
    const float* Wk   = (const float*)d_in[6];
    const float* bk   = (const float*)d_in[7];
    const float* Wv   = (const float*)d_in[8];
    const float* bv   = (const float*)d_in[9];
    const float* Ww   = (const float*)d_in[10];
    // d_in[11] (bw) cancels under softmax.

    float* ws  = (float*)d_ws;
    float* eqT = ws;                         // 512K floats [512 d][1024 n]
    float* ek  = ws + 524288;                // 512K [1024 m][512 d]
    float* vp  = ws + 1048576;               // 512K [1024 m][512 d]
    float* PT  = ws + 1572864;               // 1M  [1024 m][1024 n]
    float* out = (float*)d_out;

    const float CS = 2.8853900817779268f;    // 2*log2(e)

    proj_gemm<<<dim3(16, 8, 3), dim3(512), 0, stream>>>(q, k, v, Wq, bq, Wk, bk,
                                                        Wv, bv, eqT, ek, vp, CS);
    score_kernel<<<dim3(4, 256), dim3(256), 0, stream>>>(eqT, ek, Ww, mask, PT);
    ctx_gemm<<<dim3(16, 32), dim3(256), 0, stream>>>(PT, vp, out);
}

// Round 8
// 212.450 us; speedup vs baseline: 1.1123x; 1.1123x over previous
//
#include <hip/hip_runtime.h>
#include <hip/hip_bf16.h>
#include <float.h>

// N=1024, M=1024, D=512, fp32.
// tanh(q+k) = 1 - 2/(1+exp2(CS*(q+k))), CS=2*log2(e), exp2 factorized:
// eqT[d][n]=min(exp2(CS*qp),2^13)^T, ek[m][d]=min(exp2(CS*kp),2^13).
// s[n,m] = -2*sum_d Ww[d]/(1+eq*ek) (row-const dropped; softmax shift-inv;
// exp(s) never overflows -> no max pass). Quad-rational: 4 d-terms share ONE
// rcp (v_rcp_f32 is 1/8-rate). PT[m][n] = mask?exp(s):0.
// R8: 3 kernels. rowsum folded into score epilogue (LDS reduce + 256
// atomicAdds/block; rsum zeroed by proj block 0). ek/Ww staged in LDS per
// chunk (R5-style; R6 s_load and R7 vmem variants both regressed). proj/ctx
// rebuilt as slim high-occupancy tiles (768 / 512 blocks).
// ws (floats): eqT[512K] ek[512K] vp[512K] PT[1M] rsum[1K] = 10.5 MB.

#define NROWS 1024
#define DDIM  512
#define MDIM  1024

__device__ __forceinline__ void load_lds16(const float* g, float* l) {
    __builtin_amdgcn_global_load_lds(
        (const __attribute__((address_space(1))) void*)g,
        (__attribute__((address_space(3))) void*)l, 16, 0, 0);
}

// ---------------- K1: fused projection GEMMs (A^T-B form) --------------------
// out[R][C] = sum_k A[r][k]*B[c][k] (+bias, optional clamp(exp2*CS)).
// z=0: eqT[d][n]: A=Wq, B=q,  bias row, exp2.  R=512,  C=1024
// z=1: ek[m][d]:  A=k,  B=Wk, bias col, exp2.  R=1024, C=512
// z=2: vp[m][d]:  A=v,  B=Wv, bias col.        R=1024, C=512
// 64(R) x 32(C) tile, 768 blocks x 256 thr, 24 KB LDS -> high occupancy.
// LDS k-major with XOR swizzle: coalesced global reads, conflict-free
// transposed stores (2-way max) and conflict-free fragment reads.
__global__ __launch_bounds__(256) void proj_gemm(
    const float* __restrict__ q, const float* __restrict__ kk_,
    const float* __restrict__ v,
    const float* __restrict__ Wq, const float* __restrict__ bq,
    const float* __restrict__ Wk, const float* __restrict__ bk,
    const float* __restrict__ Wv, const float* __restrict__ bv,
    float* __restrict__ eqT, float* __restrict__ ek, float* __restrict__ vp,
    float* __restrict__ rsum, float CS)
{
    __shared__ __align__(16) float As[4096];   // 64k x 64r
    __shared__ __align__(16) float Bs[2048];   // 64k x 32c

    const int t   = threadIdx.x;
    const int bid = blockIdx.x;
    const int z   = bid >> 8;
    const int jb  = bid & 255;

    if (bid == 0) {       // zero rsum for score's atomics (kernel-boundary safe)
        rsum[t] = 0.f; rsum[t + 256] = 0.f; rsum[t + 512] = 0.f; rsum[t + 768] = 0.f;
    }

    const float* A; const float* B; const float* bias; float* out;
    int C, expo, biasRow, bi, bj;
    if (z == 0)      { A = Wq;  B = q;  bias = bq; out = eqT; C = 1024; expo = 1; biasRow = 1; bi = jb >> 5; bj = jb & 31; }
    else if (z == 1) { A = kk_; B = Wk; bias = bk; out = ek;  C = 512;  expo = 1; biasRow = 0; bi = jb >> 4; bj = jb & 15; }
    else             { A = v;   B = Wv; bias = bv; out = vp;  C = 512;  expo = 0; biasRow = 0; bi = jb >> 4; bj = jb & 15; }

    const int tx = t & 7;      // 8 col groups of 4
    const int ty = t >> 3;     // 32 row groups of 2
    const int i0 = bi * 64;
    const int j0 = bj * 32;

    float acc[2][4] = {};

    for (int k0 = 0; k0 < DDIM; k0 += 64) {
        __syncthreads();
#pragma unroll
        for (int p = 0; p < 4; ++p) {            // A: 64r x 64k
            int idx = t + p * 256;
            int r = idx >> 4, c4 = idx & 15;     // lanes sweep k: coalesced
            float4 af = *(const float4*)&A[(size_t)(i0 + r) * DDIM + k0 + c4 * 4];
            int base = (c4 * 4) * 64 + (((r >> 2) ^ c4) << 2) + (r & 3);
            As[base]       = af.x;  As[base + 64]  = af.y;
            As[base + 128] = af.z;  As[base + 192] = af.w;
        }
#pragma unroll
        for (int p = 0; p < 2; ++p) {            // B: 32c x 64k
            int idx = t + p * 256;
            int c = idx >> 4, k4 = idx & 15;
            float4 bf = *(const float4*)&B[(size_t)(j0 + c) * DDIM + k0 + k4 * 4];
            int base = (k4 * 4) * 32 + (((c >> 2) ^ (k4 & 7)) << 2) + (c & 3);
            Bs[base]      = bf.x;  Bs[base + 32] = bf.y;
            Bs[base + 64] = bf.z;  Bs[base + 96] = bf.w;
        }
        __syncthreads();
#pragma unroll
        for (int kg = 0; kg < 16; ++kg) {
            const int ao = (((ty >> 1) ^ kg) << 2) + ((ty & 1) << 1);
            const int bo = ((tx ^ (kg & 7)) << 2);
#pragma unroll
            for (int kq = 0; kq < 4; ++kq) {
                int kk = kg * 4 + kq;
                float2 a = *(const float2*)&As[kk * 64 + ao];
                float4 b = *(const float4*)&Bs[kk * 32 + bo];
                acc[0][0] = fmaf(a.x, b.x, acc[0][0]);
                acc[0][1] = fmaf(a.x, b.y, acc[0][1]);
                acc[0][2] = fmaf(a.x, b.z, acc[0][2]);
                acc[0][3] = fmaf(a.x, b.w, acc[0][3]);
                acc[1][0] = fmaf(a.y, b.x, acc[1][0]);
                acc[1][1] = fmaf(a.y, b.y, acc[1][1]);
                acc[1][2] = fmaf(a.y, b.z, acc[1][2]);
                acc[1][3] = fmaf(a.y, b.w, acc[1][3]);
            }
        }
    }

    const float CLAMP = 8192.0f;   // 2^13: quad-rational den < 2^127
#pragma unroll
    for (int i = 0; i < 2; ++i) {
        int row = i0 + ty * 2 + i;
        float ov[4];
#pragma unroll
        for (int j = 0; j < 4; ++j) {
            float bval = biasRow ? bias[row] : bias[j0 + tx * 4 + j];
            float val = acc[i][j] + bval;
            ov[j] = expo ? fminf(__builtin_amdgcn_exp2f(val * CS), CLAMP) : val;
        }
        float4 o = {ov[0], ov[1], ov[2], ov[3]};
        *(float4*)&out[(size_t)row * C + j0 + tx * 4] = o;
    }
}

// ---------------- K2: score + folded rowsum ----------------------------------
// PT[m][n] = mask[n][m] ? exp(-2*sum_d Ww[d]/(1+eqT[d][n]*ek[m][d])) : 0
// 4 waves; wave w owns m = by*4+w; lane owns 4 n. eqT chunk [32 d][256 n]
// via global_load_lds w=16; ek(4mx32d)+Ww staged in LDS per chunk (all inner
// reads homogeneous DS). Quad-rational: 1 rcp per 4 d-terms.
// Epilogue: LDS-reduce 4-wave partial rowsums -> 256 atomicAdds to rsum.
#define DCH 32
__global__ __launch_bounds__(256) void score_kernel(const float* __restrict__ eqT,
                                                    const float* __restrict__ ek,
                                                    const float* __restrict__ Ww,
                                                    const int* __restrict__ mask,
                                                    float* __restrict__ PT,
                                                    float* __restrict__ rsum)
{
    __shared__ __align__(16) float ks[DCH * 256];   // 32 KB
    __shared__ __align__(16) float es[4 * DCH];
    __shared__ __align__(16) float wws[DCH];
    const int t    = threadIdx.x;
    const int lane = t & 63;
    const int w    = t >> 6;
    const int n0   = blockIdx.x * 256;
    const int m0   = blockIdx.y * 4;

    float acc[4] = {};

    for (int d0 = 0; d0 < DDIM; d0 += DCH) {
        __syncthreads();
#pragma unroll
        for (int i = 0; i < 8; ++i) {
            int r = w * 8 + i;                                   // wave-uniform
            load_lds16(eqT + (size_t)(d0 + r) * NROWS + n0 + lane * 4,
                       &ks[r * 256]);
        }
        if (t < 128) {
            es[t] = ek[(size_t)(m0 + (t >> 5)) * DDIM + d0 + (t & 31)];
        } else if (t < 160) {
            wws[t - 128] = Ww[d0 + t - 128];
        }
        __syncthreads();   // drains vmcnt -> staged data visible

#pragma unroll
        for (int dq = 0; dq < DCH; dq += 4) {
            float4 eg = *(const float4*)&es[w * DCH + dq];       // ds broadcast
            float4 wg = *(const float4*)&wws[dq];                // ds broadcast
            float4 k0v = *(const float4*)&ks[(dq + 0) * 256 + lane * 4];
            float4 k1v = *(const float4*)&ks[(dq + 1) * 256 + lane * 4];
            float4 k2v = *(const float4*)&ks[(dq + 2) * 256 + lane * 4];
            float4 k3v = *(const float4*)&ks[(dq + 3) * 256 + lane * 4];
            float kv0[4] = {k0v.x, k0v.y, k0v.z, k0v.w};
            float kv1[4] = {k1v.x, k1v.y, k1v.z, k1v.w};
            float kv2[4] = {k2v.x, k2v.y, k2v.z, k2v.w};
            float kv3[4] = {k3v.x, k3v.y, k3v.z, k3v.w};
#pragma unroll
            for (int j = 0; j < 4; ++j) {
                float A0 = fmaf(kv0[j], eg.x, 1.0f);
                float A1 = fmaf(kv1[j], eg.y, 1.0f);
                float A2 = fmaf(kv2[j], eg.z, 1.0f);
                float A3 = fmaf(kv3[j], eg.w, 1.0f);
                float n01 = fmaf(wg.y, A0, wg.x * A1);
                float d01 = A0 * A1;
                float n23 = fmaf(wg.w, A2, wg.z * A3);
                float d23 = A2 * A3;
                float num = fmaf(n01, d23, n23 * d01);
                float den = d01 * d23;
                acc[j] = fmaf(num, __builtin_amdgcn_rcpf(den), acc[j]);
            }
        }
    }

    const float C2 = -2.8853900817779268f;   // -2*log2(e)
    const int m  = m0 + w;
    const int nb = n0 + lane * 4;
    float ov[4];
#pragma unroll
    for (int j = 0; j < 4; ++j) {
        int mk = mask[(size_t)(nb + j) * MDIM + m];
        ov[j] = mk ? __builtin_amdgcn_exp2f(acc[j] * C2) : 0.f;
    }
    float4 o = {ov[0], ov[1], ov[2], ov[3]};
    *(float4*)&PT[(size_t)m * NROWS + nb] = o;

    // folded rowsum: partials over this block's 4 m for each of 256 n
    __syncthreads();
    *(float4*)&ks[t * 4] = o;          // ks[w*256 + lane*4 + j], local n = lane*4+j
    __syncthreads();
    float tot = ks[t] + ks[256 + t] + ks[512 + t] + ks[768 + t];
    atomicAdd(&rsum[n0 + t], tot);     // 256 atomics/block over 1024 addrs
}

// ---------------- K3: context GEMM + normalize -------------------------------
// out[n][d] = (sum_m PT[m][n]*vp[m][d]) * rcp(rsum[n])
// 32(n) x 32(d) tile, grid (16 d,32 n) = 512 blocks, 16 KB LDS, ~40 VGPR.
__global__ __launch_bounds__(256) void ctx_gemm(const float* __restrict__ PT,
                                                const float* __restrict__ vp,
                                                const float* __restrict__ rsum,
                                                float* __restrict__ out)
{
    __shared__ __align__(16) float pts[64 * 32];   // [m][n]
    __shared__ __align__(16) float vs[64 * 32];    // [m][d]
    const int t  = threadIdx.x;
    const int tx = t & 15;      // 2 d
    const int ty = t >> 4;      // 2 n
    const int d0 = blockIdx.x * 32;
    const int n0 = blockIdx.y * 32;

    float acc[2][2] = {};

    for (int m0 = 0; m0 < MDIM; m0 += 64) {
        __syncthreads();
#pragma unroll
        for (int p = 0; p < 2; ++p) {
            int idx = t + p * 256;
            int r = idx >> 3, c4 = idx & 7;
            *(float4*)&pts[r * 32 + c4 * 4] =
                *(const float4*)&PT[(size_t)(m0 + r) * NROWS + n0 + c4 * 4];
            *(float4*)&vs[r * 32 + c4 * 4] =
                *(const float4*)&vp[(size_t)(m0 + r) * DDIM + d0 + c4 * 4];
        }
        __syncthreads();
#pragma unroll 16
        for (int mm = 0; mm < 64; ++mm) {
            float2 a = *(const float2*)&pts[mm * 32 + ty * 2];   // broadcast
            float2 b = *(const float2*)&vs[mm * 32 + tx * 2];    // broadcast
            acc[0][0] = fmaf(a.x, b.x, acc[0][0]);
            acc[0][1] = fmaf(a.x, b.y, acc[0][1]);
            acc[1][0] = fmaf(a.y, b.x, acc[1][0]);
            acc[1][1] = fmaf(a.y, b.y, acc[1][1]);
        }
    }

#pragma unroll
    for (int i = 0; i < 2; ++i) {
        int n = n0 + ty * 2 + i;
        float inv = __builtin_amdgcn_rcpf(rsum[n]);
        float2 o = {acc[i][0] * inv, acc[i][1] * inv};
        *(float2*)&out[(size_t)n * DDIM + d0 + tx * 2] = o;
    }
}

extern "C" void kernel_launch(void* const* d_in, const int* in_sizes, int n_in,
                              void* d_out, int out_size, void* d_ws, size_t ws_size,
                              hipStream_t stream)
{
    const float* q    = (const float*)d_in[0];
    const float* k    = (const float*)d_in[1];
    const float* v    = (const float*)d_in[2];
    const int*   mask = (const int*)d_in[3];
    const float* Wq   = (const float*)d_in[4];
    const float* bq   = (const float*)d_in[5];
    const float* Wk   = (const float*)d_in[6];
    const float* bk   = (const float*)d_in[7];
    const float* Wv   = (const float*)d_in[8];
    const float* bv   = (const float*)d_in[9];
    const float* Ww   = (const float*)d_in[10];
    // d_in[11] (bw) cancels under softmax.

    float* ws   = (float*)d_ws;
    float* eqT  = ws;                        // 512K floats [512 d][1024 n]
    float* ek   = ws + 524288;               // 512K [1024 m][512 d]
    float* vp   = ws + 1048576;              // 512K [1024 m][512 d]
    float* PT   = ws + 1572864;              // 1M  [1024 m][1024 n]
    float* rsum = ws + 2621440;              // 1K
    float* out  = (float*)d_out;

    const float CS = 2.8853900817779268f;    // 2*log2(e)

    proj_gemm<<<dim3(768), dim3(256), 0, stream>>>(q, k, v, Wq, bq, Wk, bk,
                                                   Wv, bv, eqT, ek, vp, rsum, CS);
    score_kernel<<<dim3(4, 256), dim3(256), 0, stream>>>(eqT, ek, Ww, mask, PT, rsum);
    ctx_gemm<<<dim3(16, 32), dim3(256), 0, stream>>>(PT, vp, rsum, out);
}

// Round 9
// 199.363 us; speedup vs baseline: 1.1853x; 1.0656x over previous
//
#include <hip/hip_runtime.h>
#include <hip/hip_bf16.h>
#include <float.h>

// N=1024, M=1024, D=512, fp32.
// tanh(q+k) = 1 - 2/(1+exp2(CS*(q+k))), CS=2*log2(e), exp2 factorized:
// eqT[d][n]=min(exp2(CS*qp),2^13)^T, ek[m][d]=min(exp2(CS*kp),2^13).
// s[n,m] = -2*sum_d Ww[d]/(1+eq*ek) (row-const dropped; softmax shift-inv;
// exp(s) never overflows -> no max pass). Quad-rational: 4 d-terms share ONE
// rcp. PT[m][n] = mask?exp(s):0; rowsum folded into score (atomicAdd rsum).
// R9 theory: ALL phases were LDS-pipe-bound (~12cyc/b128 shared per CU).
// Score: wave now owns 4 m -> each ks read amortized 4x. proj back to 64x64
// 4x4 (16 fma / 2 b128). ctx 64x64 4x4, m-split x2, normalized atomicAdd
// into out (out zeroed by proj z==0 blocks).
// ws (floats): eqT[512K] ek[512K] vp[512K] PT[1M] rsum[1K] = 10.5 MB.

#define NROWS 1024
#define DDIM  512
#define MDIM  1024

__device__ __forceinline__ void load_lds16(const float* g, float* l) {
    __builtin_amdgcn_global_load_lds(
        (const __attribute__((address_space(1))) void*)g,
        (__attribute__((address_space(3))) void*)l, 16, 0, 0);
}

// ---------------- K1: fused projection GEMMs (A^T-B form) --------------------
// out[R][C] = sum_k A[r][k]*B[c][k] (+bias, optional clamp(exp2*CS)).
// z=0: eqT[d][n]: A=Wq, B=q,  bias row, exp2.  R=512,  C=1024
// z=1: ek[m][d]:  A=k,  B=Wk, bias col, exp2.  R=1024, C=512
// z=2: vp[m][d]:  A=v,  B=Wv, bias col.        R=1024, C=512
// 64x64 tile, 4x4/thread (16 fma per 2 b128 reads), XOR-swizzled k-major LDS
// (coalesced global reads + conflict-free stores/reads), register prefetch.
// z==0 blocks also zero `out` (for ctx atomics); block (0,0,0) zeros rsum.
__global__ __launch_bounds__(256) void proj_gemm(
    const float* __restrict__ q, const float* __restrict__ kk_,
    const float* __restrict__ v,
    const float* __restrict__ Wq, const float* __restrict__ bq,
    const float* __restrict__ Wk, const float* __restrict__ bk,
    const float* __restrict__ Wv, const float* __restrict__ bv,
    float* __restrict__ eqT, float* __restrict__ ek, float* __restrict__ vp,
    float* __restrict__ rsum, float* __restrict__ outz, float CS)
{
    __shared__ __align__(16) float As[4096];
    __shared__ __align__(16) float Bs[4096];

    const float* A; const float* B; const float* bias; float* out;
    int C, expo, biasRow;
    if (blockIdx.z == 0)      { A = Wq;  B = q;  bias = bq; out = eqT; C = 1024; expo = 1; biasRow = 1; }
    else if (blockIdx.z == 1) { A = kk_; B = Wk; bias = bk; out = ek;  C = 512;  expo = 1; biasRow = 0; }
    else                      { A = v;   B = Wv; bias = bv; out = vp;  C = 512;  expo = 0; biasRow = 0; }

    const int bi = (blockIdx.z == 0) ? blockIdx.y : blockIdx.x;   // R tile
    const int bj = (blockIdx.z == 0) ? blockIdx.x : blockIdx.y;   // C tile

    const int t  = threadIdx.x;
    const int tx = t & 15;
    const int ty = t >> 4;
    const int i0 = bi * 64;
    const int j0 = bj * 64;

    // zero out (128 z==0 blocks x 4096 floats) and rsum (block 0)
    if (blockIdx.z == 0) {
        const int jb = blockIdx.y * 16 + blockIdx.x;
        float4 zz = {0.f, 0.f, 0.f, 0.f};
#pragma unroll
        for (int p = 0; p < 4; ++p)
            *(float4*)&outz[(size_t)jb * 4096 + (t + p * 256) * 4] = zz;
        if (jb == 0) *(float4*)&rsum[t * 4] = zz;
    }

    float acc[4][4] = {};
    float4 pa[4], pb[4];

#pragma unroll
    for (int p = 0; p < 4; ++p) {
        int idx = t + p * 256;
        int r = idx >> 4, c4 = idx & 15;
        pa[p] = *(const float4*)&A[(size_t)(i0 + r) * DDIM + c4 * 4];
        pb[p] = *(const float4*)&B[(size_t)(j0 + r) * DDIM + c4 * 4];
    }

    for (int kc = 0; kc < 8; ++kc) {
        __syncthreads();
#pragma unroll
        for (int p = 0; p < 4; ++p) {
            int idx = t + p * 256;
            int r = idx >> 4, c4 = idx & 15;
            int base = (c4 * 4) * 64 + (((r >> 2) ^ c4) << 2) + (r & 3);
            As[base]       = pa[p].x;  As[base + 64]  = pa[p].y;
            As[base + 128] = pa[p].z;  As[base + 192] = pa[p].w;
            Bs[base]       = pb[p].x;  Bs[base + 64]  = pb[p].y;
            Bs[base + 128] = pb[p].z;  Bs[base + 192] = pb[p].w;
        }
        __syncthreads();
        if (kc < 7) {
            const int k0 = (kc + 1) * 64;
#pragma unroll
            for (int p = 0; p < 4; ++p) {
                int idx = t + p * 256;
                int r = idx >> 4, c4 = idx & 15;
                pa[p] = *(const float4*)&A[(size_t)(i0 + r) * DDIM + k0 + c4 * 4];
                pb[p] = *(const float4*)&B[(size_t)(j0 + r) * DDIM + k0 + c4 * 4];
            }
        }
#pragma unroll
        for (int kg = 0; kg < 16; ++kg) {
            const int ao = ((ty ^ kg) << 2);
            const int bo = ((tx ^ kg) << 2);
#pragma unroll
            for (int kq = 0; kq < 4; ++kq) {
                int kk = kg * 4 + kq;
                float4 a = *(const float4*)&As[kk * 64 + ao];
                float4 b = *(const float4*)&Bs[kk * 64 + bo];
                float av4[4] = {a.x, a.y, a.z, a.w};
                float bv4[4] = {b.x, b.y, b.z, b.w};
#pragma unroll
                for (int i = 0; i < 4; ++i)
#pragma unroll
                    for (int j = 0; j < 4; ++j)
                        acc[i][j] = fmaf(av4[i], bv4[j], acc[i][j]);
            }
        }
    }

    const float CLAMP = 8192.0f;   // 2^13: quad-rational den < 2^127
#pragma unroll
    for (int i = 0; i < 4; ++i) {
        int row = i0 + ty * 4 + i;
        float ov[4];
#pragma unroll
        for (int j = 0; j < 4; ++j) {
            float bval = biasRow ? bias[row] : bias[j0 + tx * 4 + j];
            float val = acc[i][j] + bval;
            ov[j] = expo ? fminf(__builtin_amdgcn_exp2f(val * CS), CLAMP) : val;
        }
        float4 o = {ov[0], ov[1], ov[2], ov[3]};
        *(float4*)&out[(size_t)row * C + j0 + tx * 4] = o;
    }
}

// ---------------- K2: score + folded rowsum ----------------------------------
// PT[m][n] = mask[n][m] ? exp(-2*sum_d Ww[d]/(1+eqT[d][n]*ek[m][d])) : 0
// Block: 4 waves; wave w owns FOUR m (ks reads amortized 4x); lane owns 2 n.
// Block covers 16 m x 128 n. Grid (8 n-chunks, 64 m-chunks) = 512 blocks.
// eqT chunk [32 d][128 n] via global_load_lds w=16 (2 rows per instr);
// ek(16m x 32d)+Ww staged in LDS (homogeneous DS; broadcast reads).
#define DCH  32
#define SNCH 128
__global__ __launch_bounds__(256) void score_kernel(const float* __restrict__ eqT,
                                                    const float* __restrict__ ek,
                                                    const float* __restrict__ Ww,
                                                    const int* __restrict__ mask,
                                                    float* __restrict__ PT,
                                                    float* __restrict__ rsum)
{
    __shared__ __align__(16) float ks[DCH * SNCH];   // 16 KB
    __shared__ __align__(16) float es[16 * DCH];     // 2 KB
    __shared__ __align__(16) float wws[DCH];
    const int t    = threadIdx.x;
    const int lane = t & 63;
    const int w    = t >> 6;
    const int n0   = blockIdx.x * SNCH;
    const int m0   = blockIdx.y * 16;

    float acc[4][2] = {};

    for (int d0 = 0; d0 < DDIM; d0 += DCH) {
        __syncthreads();
#pragma unroll
        for (int i = 0; i < 4; ++i) {
            int r2 = w * 8 + i * 2;                              // wave-uniform
            const float* g = eqT + (size_t)(d0 + r2 + (lane >> 5)) * NROWS
                             + n0 + (lane & 31) * 4;
            load_lds16(g, &ks[r2 * SNCH]);
        }
#pragma unroll
        for (int p = 0; p < 2; ++p) {
            int idx = t + p * 256;
            int ml = idx >> 5, dd = idx & 31;
            es[ml * DCH + dd] = ek[(size_t)(m0 + ml) * DDIM + d0 + dd];
        }
        if (t < DCH) wws[t] = Ww[d0 + t];
        __syncthreads();   // drains vmcnt -> staged data visible

#pragma unroll
        for (int dq = 0; dq < DCH; dq += 4) {
            float2 k0 = *(const float2*)&ks[(dq + 0) * SNCH + lane * 2];
            float2 k1 = *(const float2*)&ks[(dq + 1) * SNCH + lane * 2];
            float2 k2 = *(const float2*)&ks[(dq + 2) * SNCH + lane * 2];
            float2 k3 = *(const float2*)&ks[(dq + 3) * SNCH + lane * 2];
            float4 wg = *(const float4*)&wws[dq];                // broadcast
#pragma unroll
            for (int mm = 0; mm < 4; ++mm) {
                float4 eg = *(const float4*)&es[(w * 4 + mm) * DCH + dq]; // bc
#pragma unroll
                for (int j = 0; j < 2; ++j) {
                    float A0 = fmaf(j ? k0.y : k0.x, eg.x, 1.0f);
                    float A1 = fmaf(j ? k1.y : k1.x, eg.y, 1.0f);
                    float A2 = fmaf(j ? k2.y : k2.x, eg.z, 1.0f);
                    float A3 = fmaf(j ? k3.y : k3.x, eg.w, 1.0f);
                    float n01 = fmaf(wg.y, A0, wg.x * A1);
                    float d01 = A0 * A1;
                    float n23 = fmaf(wg.w, A2, wg.z * A3);
                    float d23 = A2 * A3;
                    float num = fmaf(n01, d23, n23 * d01);
                    float den = d01 * d23;
                    acc[mm][j] = fmaf(num, __builtin_amdgcn_rcpf(den), acc[mm][j]);
                }
            }
        }
    }

    const float C2 = -2.8853900817779268f;   // -2*log2(e)
    const int n = n0 + lane * 2;
    float rs0 = 0.f, rs1 = 0.f;
#pragma unroll
    for (int mm = 0; mm < 4; ++mm) {
        int m = m0 + w * 4 + mm;
        int mk0 = mask[(size_t)n * MDIM + m];
        int mk1 = mask[(size_t)(n + 1) * MDIM + m];
        float2 o;
        o.x = mk0 ? __builtin_amdgcn_exp2f(acc[mm][0] * C2) : 0.f;
        o.y = mk1 ? __builtin_amdgcn_exp2f(acc[mm][1] * C2) : 0.f;
        rs0 += o.x; rs1 += o.y;
        *(float2*)&PT[(size_t)m * NROWS + n] = o;
    }

    // folded rowsum: 4-wave LDS reduce (reuse ks), 128 atomics/block
    __syncthreads();
    ks[w * SNCH + lane * 2]     = rs0;
    ks[w * SNCH + lane * 2 + 1] = rs1;
    __syncthreads();
    if (t < SNCH) {
        float tot = (ks[t] + ks[SNCH + t]) + (ks[2 * SNCH + t] + ks[3 * SNCH + t]);
        atomicAdd(&rsum[n0 + t], tot);
    }
}

// ---------------- K3: context GEMM, m-split x2, normalized atomics -----------
// out[n][d] += (sum_{m in half} PT[m][n]*vp[m][d]) * rcp(rsum[n])
// 64(n) x 64(d) tile, 4x4/thread, grid (8 d, 16 n, 2 m-halves) = 256 blocks.
// Natural m-major LDS staging (stride 68: coalesced stores, broadcast/2-way
// reads). out pre-zeroed by proj.
__global__ __launch_bounds__(256) void ctx_gemm(const float* __restrict__ PT,
                                                const float* __restrict__ vp,
                                                const float* __restrict__ rsum,
                                                float* __restrict__ out)
{
    __shared__ __align__(16) float pts[64 * 68];
    __shared__ __align__(16) float vs[64 * 68];
    const int t  = threadIdx.x;
    const int tx = t & 15;
    const int ty = t >> 4;
    const int d0 = blockIdx.x * 64;
    const int n0 = blockIdx.y * 64;
    const int mb = blockIdx.z * 512;

    float acc[4][4] = {};

    for (int m0 = mb; m0 < mb + 512; m0 += 64) {
        __syncthreads();
#pragma unroll
        for (int p = 0; p < 4; ++p) {
            int idx = t + p * 256;
            int r = idx >> 4, c4 = idx & 15;
            *(float4*)&pts[r * 68 + c4 * 4] =
                *(const float4*)&PT[(size_t)(m0 + r) * NROWS + n0 + c4 * 4];
            *(float4*)&vs[r * 68 + c4 * 4] =
                *(const float4*)&vp[(size_t)(m0 + r) * DDIM + d0 + c4 * 4];
        }
        __syncthreads();
#pragma unroll 8
        for (int mm = 0; mm < 64; ++mm) {
            float4 a = *(const float4*)&pts[mm * 68 + ty * 4];   // broadcast
            float4 b = *(const float4*)&vs[mm * 68 + tx * 4];    // 2-way free
            float av4[4] = {a.x, a.y, a.z, a.w};
            float bv4[4] = {b.x, b.y, b.z, b.w};
#pragma unroll
            for (int i = 0; i < 4; ++i)
#pragma unroll
                for (int j = 0; j < 4; ++j)
                    acc[i][j] = fmaf(av4[i], bv4[j], acc[i][j]);
        }
    }

#pragma unroll
    for (int i = 0; i < 4; ++i) {
        int nrow = n0 + ty * 4 + i;
        float inv = __builtin_amdgcn_rcpf(rsum[nrow]);
#pragma unroll
        for (int j = 0; j < 4; ++j)
            atomicAdd(&out[(size_t)nrow * DDIM + d0 + tx * 4 + j], acc[i][j] * inv);
    }
}

extern "C" void kernel_launch(void* const* d_in, const int* in_sizes, int n_in,
                              void* d_out, int out_size, void* d_ws, size_t ws_size,
                              hipStream_t stream)
{
    const float* q    = (const float*)d_in[0];
    const float* k    = (const float*)d_in[1];
    const float* v    = (const float*)d_in[2];
    const int*   mask = (const int*)d_in[3];
    const float* Wq   = (const float*)d_in[4];
    const float* bq   = (const float*)d_in[5];
    const float* Wk   = (const float*)d_in[6];
    const float* bk   = (const float*)d_in[7];
    const float* Wv   = (const float*)d_in[8];
    const float* bv   = (const float*)d_in[9];
    const float* Ww   = (const float*)d_in[10];
    // d_in[11] (bw) cancels under softmax.

    float* ws   = (float*)d_ws;
    float* eqT  = ws;                        // 512K floats [512 d][1024 n]
    float* ek   = ws + 524288;               // 512K [1024 m][512 d]
    float* vp   = ws + 1048576;              // 512K [1024 m][512 d]
    float* PT   = ws + 1572864;              // 1M  [1024 m][1024 n]
    float* rsum = ws + 2621440;              // 1K
    float* out  = (float*)d_out;

    const float CS = 2.8853900817779268f;    // 2*log2(e)

    proj_gemm<<<dim3(16, 8, 3), dim3(256), 0, stream>>>(q, k, v, Wq, bq, Wk, bk,
                                                        Wv, bv, eqT, ek, vp,
                                                        rsum, out, CS);
    score_kernel<<<dim3(8, 64), dim3(256), 0, stream>>>(eqT, ek, Ww, mask, PT, rsum);
    ctx_gemm<<<dim3(8, 16, 2), dim3(256), 0, stream>>>(PT, vp, rsum, out);
}

// Round 10
// 181.660 us; speedup vs baseline: 1.3008x; 1.0975x over previous
//
#include <hip/hip_runtime.h>
#include <hip/hip_bf16.h>
#include <float.h>

// N=1024, M=1024, D=512, fp32 in/out.
// tanh(q+k) = 1 - 2/(1+exp2(CS*(q+k))), CS=2*log2(e), exp2 factorized:
// eqT[d][n]=min(exp2(CS*qp),2^13)^T, ek[m][d]=min(exp2(CS*kp),2^13).
// s[n,m] = -2*sum_d Ww[d]/(1+eq*ek) (row-const dropped; softmax shift-inv;
// no max pass needed). Quad-rational: 4 d-terms share ONE rcp.
// R10: proj and ctx moved to MFMA 16x16x32 bf16 with hi/lo split (3-term
// hh+hl+lh = fp32-grade accuracy). proj emits vpT as bf16 h/l [d][m]; score
// emits P as bf16 h/l [n][m] + atomic rowsums; ctx is LDS-free global-frag
// MFMA. Score keeps R9 rational-VALU form.
// ws: eqT 2MB | ek 2MB | vph/vpl 2MB | Ph/Pl 4MB | rsum 4KB = 10.5 MB.

#define NROWS 1024
#define DDIM  512
#define MDIM  1024

typedef __attribute__((ext_vector_type(8))) short s8v;    // 8 bf16, 4 VGPR
typedef __attribute__((ext_vector_type(4))) float f4v;

__device__ __forceinline__ ushort f2bf(float f) {
    unsigned u = __float_as_uint(f);
    u = u + 0x7FFFu + ((u >> 16) & 1u);          // RNE
    return (ushort)(u >> 16);
}
__device__ __forceinline__ float bf2f(ushort h) {
    return __uint_as_float(((unsigned)h) << 16);
}

__device__ __forceinline__ void load_lds16(const float* g, float* l) {
    __builtin_amdgcn_global_load_lds(
        (const __attribute__((address_space(1))) void*)g,
        (__attribute__((address_space(3))) void*)l, 16, 0, 0);
}

// ---------------- K1: fused projection GEMMs (MFMA, A^T-B form) --------------
// out[R][C] = sum_k A[r][k]*B[c][k] (+bias, epilogue per z).
// z=0: eqT[d][n]: A=Wq(512xK), B=q(1024xK),  bias bq[row], exp2+clamp, fp32
// z=1: ek[m][d]:  A=k(1024xK), B=Wk(512xK),  bias bk[col], exp2+clamp, fp32
// z=2: vpT[d][m]: A=Wv(512xK), B=v(1024xK),  bias bv[row], bf16 h/l out
// 64x64 tile/block, 4 waves (2x2 of 32x32), BK=64. fp32 global -> bf16 h+l
// LDS (16B-block XOR swizzle: conflict-free stores + frag reads).
// MFMA frag: A[m=lane&15][k=quad*8+j]; D: col=lane&15,row=quad*4+reg.
__global__ __launch_bounds__(256) void proj_gemm(
    const float* __restrict__ q, const float* __restrict__ kk_,
    const float* __restrict__ v,
    const float* __restrict__ Wq, const float* __restrict__ bq,
    const float* __restrict__ Wk, const float* __restrict__ bk,
    const float* __restrict__ Wv, const float* __restrict__ bv,
    float* __restrict__ eqT, float* __restrict__ ek,
    ushort* __restrict__ vph, ushort* __restrict__ vpl,
    float* __restrict__ rsum, float CS)
{
    __shared__ ushort Ah[4096], Al[4096], Bh[4096], Bl[4096];   // 32 KB

    const float* A; const float* B; const float* bias;
    int biasRow;
    if (blockIdx.z == 0)      { A = Wq;  B = q;   bias = bq; biasRow = 1; }
    else if (blockIdx.z == 1) { A = kk_; B = Wk;  bias = bk; biasRow = 0; }
    else                      { A = Wv;  B = v;   bias = bv; biasRow = 1; }

    // z=0,2: R=512 (8 y-tiles) x C=1024 (16 x-tiles); z=1: R=1024 x C=512
    const int bi = (blockIdx.z == 1) ? blockIdx.x : blockIdx.y;
    const int bj = (blockIdx.z == 1) ? blockIdx.y : blockIdx.x;

    const int t    = threadIdx.x;
    const int lane = t & 63;
    const int w    = t >> 6;
    const int lm   = lane & 15;
    const int lq   = lane >> 4;
    const int i0   = bi * 64;
    const int j0   = bj * 64;
    const int mh   = (w >> 1) * 32;       // wave's row-half
    const int nh   = (w & 1) * 32;        // wave's col-half

    if (blockIdx.z == 0 && bi == 0 && bj == 0) {
        float4 zz = {0.f, 0.f, 0.f, 0.f};
        *(float4*)&rsum[t * 4] = zz;      // zero rsum for score's atomics
    }

    f4v acc[2][2] = {{{0.f,0.f,0.f,0.f},{0.f,0.f,0.f,0.f}},
                     {{0.f,0.f,0.f,0.f},{0.f,0.f,0.f,0.f}}};
    float4 pa[4], pb[4];

    const int sr = t >> 4, sc4 = t & 15;  // staging row / k-quad
#pragma unroll
    for (int p = 0; p < 4; ++p) {
        int r = sr + p * 16;
        pa[p] = *(const float4*)&A[(size_t)(i0 + r) * DDIM + sc4 * 4];
        pb[p] = *(const float4*)&B[(size_t)(j0 + r) * DDIM + sc4 * 4];
    }

    for (int kc = 0; kc < 8; ++kc) {
        __syncthreads();
#pragma unroll
        for (int p = 0; p < 4; ++p) {
            int r = sr + p * 16;
            // 4 k-values at c4*4 live in one swizzled 16B block
            int ad = r * 64 + (((sc4 >> 1) ^ (r & 7)) << 3) + (sc4 & 1) * 4;
            float af[4] = {pa[p].x, pa[p].y, pa[p].z, pa[p].w};
            float bf[4] = {pb[p].x, pb[p].y, pb[p].z, pb[p].w};
            ushort ah4[4], al4[4], bh4[4], bl4[4];
#pragma unroll
            for (int e = 0; e < 4; ++e) {
                ah4[e] = f2bf(af[e]); al4[e] = f2bf(af[e] - bf2f(ah4[e]));
                bh4[e] = f2bf(bf[e]); bl4[e] = f2bf(bf[e] - bf2f(bh4[e]));
            }
            *(ushort4*)&Ah[ad] = *(ushort4*)ah4;
            *(ushort4*)&Al[ad] = *(ushort4*)al4;
            *(ushort4*)&Bh[ad] = *(ushort4*)bh4;
            *(ushort4*)&Bl[ad] = *(ushort4*)bl4;
        }
        __syncthreads();
        if (kc < 7) {
            const int k0 = (kc + 1) * 64;
#pragma unroll
            for (int p = 0; p < 4; ++p) {
                int r = sr + p * 16;
                pa[p] = *(const float4*)&A[(size_t)(i0 + r) * DDIM + k0 + sc4 * 4];
                pb[p] = *(const float4*)&B[(size_t)(j0 + r) * DDIM + k0 + sc4 * 4];
            }
        }
#pragma unroll
        for (int ks = 0; ks < 2; ++ks) {
            const int kb = ks * 4 + lq;
            s8v afh[2], afl[2], bfh[2], bfl[2];
#pragma unroll
            for (int g = 0; g < 2; ++g) {
                int ra = mh + g * 16 + lm;
                int rb = nh + g * 16 + lm;
                int aa = ra * 64 + ((kb ^ (ra & 7)) << 3);
                int ab = rb * 64 + ((kb ^ (rb & 7)) << 3);
                afh[g] = *(const s8v*)&Ah[aa];
                afl[g] = *(const s8v*)&Al[aa];
                bfh[g] = *(const s8v*)&Bh[ab];
                bfl[g] = *(const s8v*)&Bl[ab];
            }
#pragma unroll
            for (int mi = 0; mi < 2; ++mi)
#pragma unroll
                for (int ni = 0; ni < 2; ++ni) {
                    acc[mi][ni] = __builtin_amdgcn_mfma_f32_16x16x32_bf16(
                        afh[mi], bfh[ni], acc[mi][ni], 0, 0, 0);
                    acc[mi][ni] = __builtin_amdgcn_mfma_f32_16x16x32_bf16(
                        afh[mi], bfl[ni], acc[mi][ni], 0, 0, 0);
                    acc[mi][ni] = __builtin_amdgcn_mfma_f32_16x16x32_bf16(
                        afl[mi], bfh[ni], acc[mi][ni], 0, 0, 0);
                }
        }
    }

    const float CLAMP = 8192.0f;   // 2^13: quad-rational den < 2^127
#pragma unroll
    for (int mi = 0; mi < 2; ++mi) {
#pragma unroll
        for (int ni = 0; ni < 2; ++ni) {
#pragma unroll
            for (int p = 0; p < 4; ++p) {
                int row = i0 + mh + mi * 16 + lq * 4 + p;
                int col = j0 + nh + ni * 16 + lm;
                float val = acc[mi][ni][p] + (biasRow ? bias[row] : bias[col]);
                if (blockIdx.z == 0) {
                    eqT[(size_t)row * 1024 + col] =
                        fminf(__builtin_amdgcn_exp2f(val * CS), CLAMP);
                } else if (blockIdx.z == 1) {
                    ek[(size_t)row * 512 + col] =
                        fminf(__builtin_amdgcn_exp2f(val * CS), CLAMP);
                } else {
                    ushort h = f2bf(val);
                    vph[(size_t)row * 1024 + col] = h;
                    vpl[(size_t)row * 1024 + col] = f2bf(val - bf2f(h));
                }
            }
        }
    }
}

// ---------------- K2: score + folded rowsum (R9 body, bf16 h/l output) -------
// P[n][m] = mask[n][m] ? exp(-2*sum_d Ww[d]/(1+eqT[d][n]*ek[m][d])) : 0
// 4 waves; wave owns 4 m; lane owns 2 n. Block 16m x 128n, grid 512.
#define DCH  32
#define SNCH 128
__global__ __launch_bounds__(256) void score_kernel(const float* __restrict__ eqT,
                                                    const float* __restrict__ ek,
                                                    const float* __restrict__ Ww,
                                                    const int* __restrict__ mask,
                                                    ushort* __restrict__ Ph,
                                                    ushort* __restrict__ Pl,
                                                    float* __restrict__ rsum)
{
    __shared__ __align__(16) float ks[DCH * SNCH];   // 16 KB
    __shared__ __align__(16) float es[16 * DCH];     // 2 KB
    __shared__ __align__(16) float wws[DCH];
    const int t    = threadIdx.x;
    const int lane = t & 63;
    const int w    = t >> 6;
    const int n0   = blockIdx.x * SNCH;
    const int m0   = blockIdx.y * 16;

    float acc[4][2] = {};

    for (int d0 = 0; d0 < DDIM; d0 += DCH) {
        __syncthreads();
#pragma unroll
        for (int i = 0; i < 4; ++i) {
            int r2 = w * 8 + i * 2;                              // wave-uniform
            const float* g = eqT + (size_t)(d0 + r2 + (lane >> 5)) * NROWS
                             + n0 + (lane & 31) * 4;
            load_lds16(g, &ks[r2 * SNCH]);
        }
#pragma unroll
        for (int p = 0; p < 2; ++p) {
            int idx = t + p * 256;
            int ml = idx >> 5, dd = idx & 31;
            es[ml * DCH + dd] = ek[(size_t)(m0 + ml) * DDIM + d0 + dd];
        }
        if (t < DCH) wws[t] = Ww[d0 + t];
        __syncthreads();

#pragma unroll
        for (int dq = 0; dq < DCH; dq += 4) {
            float2 k0 = *(const float2*)&ks[(dq + 0) * SNCH + lane * 2];
            float2 k1 = *(const float2*)&ks[(dq + 1) * SNCH + lane * 2];
            float2 k2 = *(const float2*)&ks[(dq + 2) * SNCH + lane * 2];
            float2 k3 = *(const float2*)&ks[(dq + 3) * SNCH + lane * 2];
            float4 wg = *(const float4*)&wws[dq];
#pragma unroll
            for (int mm = 0; mm < 4; ++mm) {
                float4 eg = *(const float4*)&es[(w * 4 + mm) * DCH + dq];
#pragma unroll
                for (int j = 0; j < 2; ++j) {
                    float A0 = fmaf(j ? k0.y : k0.x, eg.x, 1.0f);
                    float A1 = fmaf(j ? k1.y : k1.x, eg.y, 1.0f);
                    float A2 = fmaf(j ? k2.y : k2.x, eg.z, 1.0f);
                    float A3 = fmaf(j ? k3.y : k3.x, eg.w, 1.0f);
                    float n01 = fmaf(wg.y, A0, wg.x * A1);
                    float d01 = A0 * A1;
                    float n23 = fmaf(wg.w, A2, wg.z * A3);
                    float d23 = A2 * A3;
                    float num = fmaf(n01, d23, n23 * d01);
                    float den = d01 * d23;
                    acc[mm][j] = fmaf(num, __builtin_amdgcn_rcpf(den), acc[mm][j]);
                }
            }
        }
    }

    const float C2 = -2.8853900817779268f;   // -2*log2(e)
    const int n = n0 + lane * 2;
    float rs0 = 0.f, rs1 = 0.f;
    ushort h0[4], l0[4], h1[4], l1[4];
#pragma unroll
    for (int mm = 0; mm < 4; ++mm) {
        int m = m0 + w * 4 + mm;
        int mk0 = mask[(size_t)n * MDIM + m];
        int mk1 = mask[(size_t)(n + 1) * MDIM + m];
        float o0 = mk0 ? __builtin_amdgcn_exp2f(acc[mm][0] * C2) : 0.f;
        float o1 = mk1 ? __builtin_amdgcn_exp2f(acc[mm][1] * C2) : 0.f;
        rs0 += o0; rs1 += o1;
        h0[mm] = f2bf(o0); l0[mm] = f2bf(o0 - bf2f(h0[mm]));
        h1[mm] = f2bf(o1); l1[mm] = f2bf(o1 - bf2f(h1[mm]));
    }
    {
        size_t b0 = (size_t)n * MDIM + m0 + w * 4;
        size_t b1 = (size_t)(n + 1) * MDIM + m0 + w * 4;
        *(ushort4*)&Ph[b0] = *(ushort4*)h0;
        *(ushort4*)&Pl[b0] = *(ushort4*)l0;
        *(ushort4*)&Ph[b1] = *(ushort4*)h1;
        *(ushort4*)&Pl[b1] = *(ushort4*)l1;
    }

    __syncthreads();
    ks[w * SNCH + lane * 2]     = rs0;
    ks[w * SNCH + lane * 2 + 1] = rs1;
    __syncthreads();
    if (t < SNCH) {
        float tot = (ks[t] + ks[SNCH + t]) + (ks[2 * SNCH + t] + ks[3 * SNCH + t]);
        atomicAdd(&rsum[n0 + t], tot);
    }
}

// ---------------- K3: context MFMA (LDS-free) --------------------------------
// out[n][d] = (sum_m P[n][m]*vpT[d][m]) * rcp(rsum[n])
// Wave = one 16x16 D-tile; frags loaded DIRECTLY from global bf16 h/l
// (lane pattern covers full 64B lines via the 4 quads). 3 MFMA per K=32.
// Grid (8 d-groups x 64 n-tiles) = 512 blocks x 4 waves = 2048 tiles.
__global__ __launch_bounds__(256) void ctx_gemm(const ushort* __restrict__ Ph,
                                                const ushort* __restrict__ Pl,
                                                const ushort* __restrict__ vph,
                                                const ushort* __restrict__ vpl,
                                                const float* __restrict__ rsum,
                                                float* __restrict__ out)
{
    const int t    = threadIdx.x;
    const int lane = t & 63;
    const int w    = t >> 6;
    const int lm   = lane & 15;
    const int lq   = lane >> 4;
    const int d0   = blockIdx.x * 64 + w * 16;
    const int n0   = blockIdx.y * 16;

    const ushort* pAh = Ph  + (size_t)(n0 + lm) * MDIM + lq * 8;
    const ushort* pAl = Pl  + (size_t)(n0 + lm) * MDIM + lq * 8;
    const ushort* pBh = vph + (size_t)(d0 + lm) * MDIM + lq * 8;
    const ushort* pBl = vpl + (size_t)(d0 + lm) * MDIM + lq * 8;

    f4v acc = {0.f, 0.f, 0.f, 0.f};
#pragma unroll 4
    for (int m0 = 0; m0 < MDIM; m0 += 32) {
        s8v ah = *(const s8v*)(pAh + m0);
        s8v al = *(const s8v*)(pAl + m0);
        s8v bh = *(const s8v*)(pBh + m0);
        s8v bl = *(const s8v*)(pBl + m0);
        acc = __builtin_amdgcn_mfma_f32_16x16x32_bf16(ah, bh, acc, 0, 0, 0);
        acc = __builtin_amdgcn_mfma_f32_16x16x32_bf16(ah, bl, acc, 0, 0, 0);
        acc = __builtin_amdgcn_mfma_f32_16x16x32_bf16(al, bh, acc, 0, 0, 0);
    }

#pragma unroll
    for (int p = 0; p < 4; ++p) {
        int nrow = n0 + lq * 4 + p;
        float inv = __builtin_amdgcn_rcpf(rsum[nrow]);
        out[(size_t)nrow * DDIM + d0 + lm] = acc[p] * inv;
    }
}

extern "C" void kernel_launch(void* const* d_in, const int* in_sizes, int n_in,
                              void* d_out, int out_size, void* d_ws, size_t ws_size,
                              hipStream_t stream)
{
    const float* q    = (const float*)d_in[0];
    const float* k    = (const float*)d_in[1];
    const float* v    = (const float*)d_in[2];
    const int*   mask = (const int*)d_in[3];
    const float* Wq   = (const float*)d_in[4];
    const float* bq   = (const float*)d_in[5];
    const float* Wk   = (const float*)d_in[6];
    const float* bk   = (const float*)d_in[7];
    const float* Wv   = (const float*)d_in[8];
    const float* bv   = (const float*)d_in[9];
    const float* Ww   = (const float*)d_in[10];
    // d_in[11] (bw) cancels under softmax.

    float* ws    = (float*)d_ws;
    float* eqT   = ws;                       // 512K floats [512 d][1024 n]
    float* ek    = ws + 524288;              // 512K [1024 m][512 d]
    ushort* vph  = (ushort*)(ws + 1048576);  // 512K ushorts [512 d][1024 m]
    ushort* vpl  = (ushort*)(ws + 1310720);  // 512K ushorts
    ushort* Ph   = (ushort*)(ws + 1572864);  // 1M ushorts [1024 n][1024 m]
    ushort* Pl   = (ushort*)(ws + 2097152);  // 1M ushorts
    float* rsum  = ws + 2621440;             // 1K floats
    float* out   = (float*)d_out;

    const float CS = 2.8853900817779268f;    // 2*log2(e)

    proj_gemm<<<dim3(16, 8, 3), dim3(256), 0, stream>>>(q, k, v, Wq, bq, Wk, bk,
                                                        Wv, bv, eqT, ek,
                                                        vph, vpl, rsum, CS);
    score_kernel<<<dim3(8, 64), dim3(256), 0, stream>>>(eqT, ek, Ww, mask,
                                                        Ph, Pl, rsum);
    ctx_gemm<<<dim3(8, 64), dim3(256), 0, stream>>>(Ph, Pl, vph, vpl, rsum, out);
}